// Round 9
// baseline (88.746 us; speedup 1.0000x reference)
//
#include <hip/hip_runtime.h>

#define NB    4
#define BLK   256
#define CHK   128            // points per triangle chunk
#define NCHK  32             // chunks per batch
#define NBLK3 528            // triangle blocks per batch: 32*33/2

#if __has_builtin(__builtin_amdgcn_exp2f)
#define EXPFN(x) __builtin_amdgcn_exp2f(x)
#define FSCALE 1.2011224087864498f   /* sqrt(log2(e)) */
#else
#define EXPFN(x) __expf(x)
#define FSCALE 1.0f
#endif

typedef __attribute__((ext_vector_type(8))) short short8v;   // 8 bf16 (4 VGPR)
typedef __attribute__((ext_vector_type(4))) float f32x4;

typedef unsigned int uint;
typedef unsigned short ushort;

// Round-to-nearest-even bf16 split: returns bf16 bits, rem = v - bf16(v) (exact).
__device__ __forceinline__ ushort bsplit(float v, float& rem) {
    uint u = __float_as_uint(v);
    uint r = (u + 0x7FFFu + ((u >> 16) & 1u)) >> 16;
    rem = v - __uint_as_float(r << 16);
    return (ushort)r;
}

// Fused kernel: phase 1 packs the block's 256 records (128 p-rows A-pattern,
// 128 q-rows B-pattern -- HW-verified split-bf16 packing, absmax 0.0 in
// R7/R8) into LDS; phase 2 is the verified MFMA tile loop with LDS-resident
// fragments; phase 3 reduces and atomicAdds. grid = (528, 4), 4 waves.
// LDS rows padded to 20 uints (80 B) to spread banks on ds_read_b128.
__global__ __launch_bounds__(256) void crf_fused(const float* __restrict__ images,
                                                 const float* __restrict__ segs,
                                                 float* __restrict__ out) {
    __shared__ uint FAl[CHK][20];    // feat A-pattern rows (p-side)
    __shared__ uint SAl[CHK][20];    // seg  A-pattern rows (p-side)
    __shared__ uint FBl[CHK][20];    // feat B-pattern rows (q-side)
    __shared__ uint SBl[CHK][20];    // seg  B-pattern rows (q-side)
    __shared__ float Hp[CHK];
    __shared__ float Hq[CHK];
    __shared__ float wsum[BLK / 64];

    int t = threadIdx.x;
    int n = blockIdx.y;
    int lane = t & 63;
    int w = t >> 6;
    int l15 = lane & 15;
    int lhi = lane >> 4;

    // Decode triangle block -> (p-chunk pc, q-chunk qc), qc >= pc.
    int b = blockIdx.x;                  // 0..527
    int pc = 0;
#pragma unroll
    for (int i = 1; i < NCHK; ++i) pc += (b >= (i * (2 * NCHK + 1 - i)) / 2) ? 1 : 0;
    int qc = b - (pc * (2 * NCHK + 1 - pc)) / 2 + pc;
    bool diagblk = (pc == qc);

    // ---------------- Phase 1: pack 256 records into LDS ----------------
    {
        int side = t >> 7;               // 0 = p-side (waves 0,1), 1 = q-side
        int r    = t & 127;
        int p    = (side ? qc : pc) * CHK + r;   // point index in batch
        int i = p >> 6;
        int j = p & 63;
        int off = 256 * i + 2 * j;               // pixel (2i,2j) in 128x128
        const float* img = images + (size_t)n * 3 * 16384;
        float f[5];
        f[0] = (float)j * (FSCALE / 50.0f);      // SIGMA_XY*SCALE = 50
        f[1] = (float)i * (FSCALE / 50.0f);
        f[2] = img[off]         * (FSCALE / 15.0f);   // SIGMA_RGB = 15
        f[3] = img[16384 + off] * (FSCALE / 15.0f);
        f[4] = img[32768 + off] * (FSCALE / 15.0f);
        float h = -0.5f * (f[0]*f[0] + f[1]*f[1] + f[2]*f[2] + f[3]*f[3] + f[4]*f[4]);

        const float* sg = segs + (size_t)n * 4 * 16384;
        float s[4];
#pragma unroll
        for (int k = 0; k < 4; ++k) {
            float2 u0 = *(const float2*)(sg + k * 16384 + off);
            float2 u1 = *(const float2*)(sg + k * 16384 + off + 128);
            s[k] = 0.25f * ((u0.x + u0.y) + (u1.x + u1.y));
        }

        // 3-way bf16 split of feats, 2-way split of segs (verified).
        ushort v[3][5];
        ushort tg[2][4];
#pragma unroll
        for (int c = 0; c < 5; ++c) {
            float r1, r2, dead;
            v[0][c] = bsplit(f[c], r1);
            v[1][c] = bsplit(r1, r2);
            v[2][c] = bsplit(r2, dead);
        }
#pragma unroll
        for (int c = 0; c < 4; ++c) {
            float r1, dead;
            tg[0][c] = bsplit(s[c], r1);
            tg[1][c] = bsplit(r1, dead);
        }

        uint fw[16], sw[16];
        if (side == 0) {
            // A-pattern: feats [f1 f1 f2 f1 f2 f3], segs [t1 t1 t2]
            static const int PA[6] = {0, 0, 1, 0, 1, 2};
            static const int QA[3] = {0, 0, 1};
#pragma unroll
            for (int k2 = 0; k2 < 16; ++k2) {
                int s0 = 2 * k2, s1 = s0 + 1;
                uint lo = (s0 >= 30) ? 0u : (uint)v[PA[s0 / 5]][s0 % 5];
                uint hi = (s1 >= 30) ? 0u : (uint)v[PA[s1 / 5]][s1 % 5];
                fw[k2] = lo | (hi << 16);
                lo = (s0 >= 12) ? 0u : (uint)tg[QA[s0 / 4]][s0 % 4];
                hi = (s1 >= 12) ? 0u : (uint)tg[QA[s1 / 4]][s1 % 4];
                sw[k2] = lo | (hi << 16);
            }
        } else {
            // B-pattern: feats [f1 f2 f1 f3 f2 f1], segs [t1 t2 t1]
            static const int PB[6] = {0, 1, 0, 2, 1, 0};
            static const int QB[3] = {0, 1, 0};
#pragma unroll
            for (int k2 = 0; k2 < 16; ++k2) {
                int s0 = 2 * k2, s1 = s0 + 1;
                uint lo = (s0 >= 30) ? 0u : (uint)v[PB[s0 / 5]][s0 % 5];
                uint hi = (s1 >= 30) ? 0u : (uint)v[PB[s1 / 5]][s1 % 5];
                fw[k2] = lo | (hi << 16);
                lo = (s0 >= 12) ? 0u : (uint)tg[QB[s0 / 4]][s0 % 4];
                hi = (s1 >= 12) ? 0u : (uint)tg[QB[s1 / 4]][s1 % 4];
                sw[k2] = lo | (hi << 16);
            }
        }

        uint* fd = side ? FBl[r] : FAl[r];
        uint* sd = side ? SBl[r] : SAl[r];
#pragma unroll
        for (int k = 0; k < 4; ++k) {
            *(uint4*)&fd[4 * k] = make_uint4(fw[4*k], fw[4*k+1], fw[4*k+2], fw[4*k+3]);
            *(uint4*)&sd[4 * k] = make_uint4(sw[4*k], sw[4*k+1], sw[4*k+2], sw[4*k+3]);
        }
        if (side) Hq[r] = h;
        else      Hp[r] = h;
    }
    __syncthreads();

    // ---------------- Phase 2: MFMA tile loop (verified math) ----------------
    int prow0 = w * 32;                  // wave's 32 p-rows (local)
    short8v a0  = __builtin_bit_cast(short8v, *(const uint4*)&FAl[prow0 + l15][lhi * 4]);
    short8v a1  = __builtin_bit_cast(short8v, *(const uint4*)&FAl[prow0 + 16 + l15][lhi * 4]);
    short8v sa0 = __builtin_bit_cast(short8v, *(const uint4*)&SAl[prow0 + l15][lhi * 4]);
    short8v sa1 = __builtin_bit_cast(short8v, *(const uint4*)&SAl[prow0 + 16 + l15][lhi * 4]);
    float hp0[4], hp1[4];
#pragma unroll
    for (int r = 0; r < 4; ++r) {
        hp0[r] = Hp[prow0 + lhi * 4 + r];
        hp1[r] = Hp[prow0 + 16 + lhi * 4 + r];
    }

    float accP = 0.f;   // plain tiles (doubled at the end)
    float accD = 0.f;   // diagonal-chunk tiles (explicit 2/1/0 weights)

#pragma unroll
    for (int jj = 0; jj < 8; ++jj) {
        if (diagblk && jj < 2 * w) continue;   // tile fully below both frags
        int qr = jj * 16;
        short8v bf  = __builtin_bit_cast(short8v, *(const uint4*)&FBl[qr + l15][lhi * 4]);
        short8v sbf = __builtin_bit_cast(short8v, *(const uint4*)&SBl[qr + l15][lhi * 4]);
        float hq = Hq[qr + l15];

        f32x4 cf0 = {0.f, 0.f, 0.f, 0.f};
        f32x4 cf1 = {0.f, 0.f, 0.f, 0.f};
        f32x4 cs0 = {0.f, 0.f, 0.f, 0.f};
        f32x4 cs1 = {0.f, 0.f, 0.f, 0.f};
        cf0 = __builtin_amdgcn_mfma_f32_16x16x32_bf16(a0, bf, cf0, 0, 0, 0);
        cf1 = __builtin_amdgcn_mfma_f32_16x16x32_bf16(a1, bf, cf1, 0, 0, 0);
        cs0 = __builtin_amdgcn_mfma_f32_16x16x32_bf16(sa0, sbf, cs0, 0, 0, 0);
        cs1 = __builtin_amdgcn_mfma_f32_16x16x32_bf16(sa1, sbf, cs1, 0, 0, 0);

        if (!diagblk) {
#pragma unroll
            for (int r = 0; r < 4; ++r) {
                accP = fmaf(EXPFN(cf0[r] + (hp0[r] + hq)), cs0[r], accP);
                accP = fmaf(EXPFN(cf1[r] + (hp1[r] + hq)), cs1[r], accP);
            }
        } else {
            int ql = qr + l15;                  // local q row == global offset
            int pl = prow0 + lhi * 4;           // + r (frag0); +16 for frag1
#pragma unroll
            for (int r = 0; r < 4; ++r) {
                float w0 = EXPFN(cf0[r] + (hp0[r] + hq));
                int pg0 = pl + r;
                float f0 = (ql > pg0) ? 2.0f : ((ql == pg0) ? 1.0f : 0.0f);
                accD = fmaf(w0 * f0, cs0[r], accD);
                float w1 = EXPFN(cf1[r] + (hp1[r] + hq));
                int pg1 = pg0 + 16;
                float f1 = (ql > pg1) ? 2.0f : ((ql == pg1) ? 1.0f : 0.0f);
                accD = fmaf(w1 * f1, cs1[r], accD);
            }
        }
    }

    // ---------------- Phase 3: reduce + atomic ----------------
    float acc_all = 2.0f * accP + accD;
#pragma unroll
    for (int off = 32; off > 0; off >>= 1)
        acc_all += __shfl_down(acc_all, off, 64);
    if ((t & 63) == 0) wsum[t >> 6] = acc_all;
    __syncthreads();
    if (t == 0) {
        float s = (wsum[0] + wsum[1]) + (wsum[2] + wsum[3]);
        // loss = WEIGHT * (-sum / n) = -1e-7/4 * sum
        atomicAdd(out, s * (-2.5e-8f));
    }
}

extern "C" void kernel_launch(void* const* d_in, const int* in_sizes, int n_in,
                              void* d_out, int out_size, void* d_ws, size_t ws_size,
                              hipStream_t stream) {
    const float* images = (const float*)d_in[0];
    const float* segs   = (const float*)d_in[1];
    float* out = (float*)d_out;
    (void)d_ws; (void)ws_size; (void)in_sizes; (void)n_in; (void)out_size;

    (void)hipMemsetAsync(out, 0, sizeof(float), stream);
    crf_fused<<<dim3(NBLK3, NB), dim3(256), 0, stream>>>(images, segs, out);
}